// Round 2
// baseline (55.351 us; speedup 1.0000x reference)
//
#include <hip/hip_runtime.h>

// ContinuousMask: out[b][t] = 1 unless t is inside any window [s, s+L) for
// s in starts[b][:]; computed via difference-array + block prefix sum.
// Output is compared as int32 by the harness (reference returns bool mask).

#define B_ROWS   2048
#define T_DIM    16384
#define NSEG     8192
#define LSEG     1638
#define NTHREADS 1024
#define CHUNK    (T_DIM / NTHREADS)            // 16 positions per thread
#define NWAVES   (NTHREADS / 64)               // 16
#define HSZ      (T_DIM + (T_DIM / 64) * 4)    // 17408 ints (pad 4 per 64)

// Pad-swizzle: +4 ints every 64 elements. Keeps each thread's 16-element
// chunk contiguous and 16B-aligned, rotates banks by +4 per 64-block.
__device__ __forceinline__ int sw_idx(int i) { return i + ((i >> 6) << 2); }

__global__ __launch_bounds__(NTHREADS)
void continuous_mask_kernel(const int* __restrict__ starts,
                            int* __restrict__ out) {
    __shared__ int hist[HSZ];
    __shared__ int wsum[NWAVES];

    const int row = blockIdx.x;
    const int tid = threadIdx.x;

    // ---- Phase A: zero histogram -----------------------------------------
    #pragma unroll
    for (int k = 0; k < HSZ / NTHREADS; ++k)   // 17 iters, coalesced
        hist[tid + k * NTHREADS] = 0;
    __syncthreads();

    // ---- Phase B: difference-array histogram -----------------------------
    // Packed counter: low 16 bits = #window-opens, high 16 = #window-closes.
    // Each half <= NSEG (8192) so halves never carry into each other.
    {
        const int4* sp = reinterpret_cast<const int4*>(
            starts + (size_t)row * NSEG);
        #pragma unroll
        for (int k = 0; k < NSEG / (NTHREADS * 4); ++k) {   // 2 iters
            int4 s4 = sp[tid + k * NTHREADS];               // coalesced 16B
            int sv[4] = {s4.x, s4.y, s4.z, s4.w};
            #pragma unroll
            for (int j = 0; j < 4; ++j) {
                int s = sv[j];
                atomicAdd(&hist[sw_idx(s)], 1);
                int e = s + LSEG;
                if (e < T_DIM)                  // e==T only affects cumsum[T]
                    atomicAdd(&hist[sw_idx(e)], 0x10000);
            }
        }
    }
    __syncthreads();

    // ---- Phase C: per-thread local prefix over its 16 positions ----------
    const int base = tid * CHUNK;
    int pre[CHUNK];
    int total;
    {
        const int4* h4 = reinterpret_cast<const int4*>(&hist[sw_idx(base)]);
        int run = 0;
        #pragma unroll
        for (int k = 0; k < CHUNK / 4; ++k) {
            int4 h = h4[k];                     // ds_read_b128
            int hv[4] = {h.x, h.y, h.z, h.w};
            #pragma unroll
            for (int j = 0; j < 4; ++j) {
                int hh = hv[j];
                run += (hh & 0xFFFF) - (hh >> 16);
                pre[k * 4 + j] = run;
            }
        }
        total = run;
    }

    // ---- Phase D: block-wide exclusive scan of per-thread totals ---------
    const int lane = tid & 63;
    const int wid  = tid >> 6;
    int incl = total;
    #pragma unroll
    for (int off = 1; off < 64; off <<= 1) {
        int n = __shfl_up(incl, off);           // wave64 shuffle
        if (lane >= off) incl += n;
    }
    if (lane == 63) wsum[wid] = incl;           // wave total
    __syncthreads();
    int offset = incl - total;                  // exclusive within wave
    for (int j = 0; j < wid; ++j)               // 16 broadcast LDS reads max
        offset += wsum[j];

    // ---- Phase E: emit mask (int32 0/1) ----------------------------------
    int4* op = reinterpret_cast<int4*>(out + (size_t)row * T_DIM + base);
    #pragma unroll
    for (int k = 0; k < CHUNK / 4; ++k) {
        int4 o;
        o.x = (offset + pre[k * 4 + 0] > 0) ? 0 : 1;
        o.y = (offset + pre[k * 4 + 1] > 0) ? 0 : 1;
        o.z = (offset + pre[k * 4 + 2] > 0) ? 0 : 1;
        o.w = (offset + pre[k * 4 + 3] > 0) ? 0 : 1;
        op[k] = o;
    }
}

extern "C" void kernel_launch(void* const* d_in, const int* in_sizes, int n_in,
                              void* d_out, int out_size, void* d_ws, size_t ws_size,
                              hipStream_t stream) {
    const int* starts = (const int*)d_in[0];
    int* out = (int*)d_out;
    // Shapes are fixed by the module config (B=2048, T=16384, n=0.5, l=0.1).
    continuous_mask_kernel<<<B_ROWS, NTHREADS, 0, stream>>>(starts, out);
}

// Round 3
// 31.935 us; speedup vs baseline: 1.7332x; 1.7332x over previous
//
#include <hip/hip_runtime.h>

// ContinuousMask via presence-bitmap + prefix-popcount.
// covered(t) = exists start s in [t-L+1, t]  <=>  P[t] - P[t-L] > 0
// where P = inclusive prefix popcount of the start-presence bitmap.
// Output compared as int32 (bool mask) by the harness: 1 = keep, 0 = masked.

#define B_ROWS   2048
#define T_DIM    16384
#define NSEG     8192
#define LSEG     1638
#define NTHREADS 1024
#define NWORDS   (T_DIM / 32)        // 512 bitmap words

__global__ __launch_bounds__(NTHREADS)
void continuous_mask_kernel(const int* __restrict__ starts,
                            int* __restrict__ out) {
    __shared__ unsigned bm[NWORDS];   // presence bitmap
    __shared__ int      pfx[NWORDS];  // exclusive word-prefix popcount
    __shared__ int      wsum[8];      // per-wave scan totals (512 scanned)

    const int row  = blockIdx.x;
    const int tid  = threadIdx.x;
    const int lane = tid & 63;

    // ---- Prefetch this thread's 8 starts (2 coalesced int4 loads) --------
    const int4* sp = reinterpret_cast<const int4*>(starts + (size_t)row * NSEG);
    int4 a = sp[tid];
    int4 b = sp[tid + NTHREADS];

    // ---- Zero bitmap (one wave-write) ------------------------------------
    if (tid < NWORDS) bm[tid] = 0u;
    __syncthreads();

    // ---- Build presence bitmap: 8 atomicOr per thread --------------------
    {
        int sv[8] = {a.x, a.y, a.z, a.w, b.x, b.y, b.z, b.w};
        #pragma unroll
        for (int j = 0; j < 8; ++j) {
            int s = sv[j];
            atomicOr(&bm[s >> 5], 1u << (s & 31));
        }
    }
    __syncthreads();

    // ---- Scan word popcounts (512 values; waves 8..15 compute dups) ------
    const int w = tid & (NWORDS - 1);
    unsigned myw = bm[w];
    int c = __popc(myw);
    int incl = c;
    #pragma unroll
    for (int off = 1; off < 64; off <<= 1) {
        int n = __shfl_up(incl, off);
        if (lane >= off) incl += n;
    }
    if (tid < NWORDS && lane == 63) wsum[tid >> 6] = incl;
    __syncthreads();
    if (tid < NWORDS) {
        int woff = 0;
        for (int j = 0; j < (tid >> 6); ++j) woff += wsum[j];
        pfx[w] = woff + incl - c;     // exclusive prefix of word w
    }
    __syncthreads();

    // ---- Emit: 4 int4 per thread, perfectly coalesced per instruction ----
    // int4 index gi = tid + k*1024 -> positions [4*gi, 4*gi+3].
    int4* op = reinterpret_cast<int4*>(out + (size_t)row * T_DIM);
    #pragma unroll
    for (int k = 0; k < 4; ++k) {
        int gi = tid + (k << 10);
        int g  = gi << 2;                       // base bit position (mult of 4)
        unsigned wT = bm[g >> 5];
        int      pT = pfx[g >> 5];
        int o[4];
        #pragma unroll
        for (int j = 0; j < 4; ++j) {
            int t  = g + j;
            int Pt = pT + __popc(wT & ((2u << (t & 31)) - 1));
            int u  = t - LSEG;
            int Pu = 0;
            if (u >= 0)
                Pu = pfx[u >> 5] + __popc(bm[u >> 5] & ((2u << (u & 31)) - 1));
            o[j] = (Pt > Pu) ? 0 : 1;           // covered -> 0, else 1
        }
        int4 v; v.x = o[0]; v.y = o[1]; v.z = o[2]; v.w = o[3];
        op[gi] = v;
    }
}

extern "C" void kernel_launch(void* const* d_in, const int* in_sizes, int n_in,
                              void* d_out, int out_size, void* d_ws, size_t ws_size,
                              hipStream_t stream) {
    const int* starts = (const int*)d_in[0];
    int* out = (int*)d_out;
    continuous_mask_kernel<<<B_ROWS, NTHREADS, 0, stream>>>(starts, out);
}